// Round 1
// baseline (3479.934 us; speedup 1.0000x reference)
//
#include <hip/hip_runtime.h>

#define BB 2
#define SS 128
#define SEGC 128
#define DD 768
#define RLC 16
#define HH 8
#define DKC 64
#define DVC 96
#define NN 2048          // S*RL
#define NPC 4095         // 2N-1
#define HDK 512          // H*DK
#define HDV 768          // H*DV

// ---------------- copy x -> out ----------------
__global__ __launch_bounds__(256) void copy4(const float4* __restrict__ src,
                                             float4* __restrict__ dst, int n4) {
  int i = blockIdx.x * blockDim.x + threadIdx.x;
  int stride = gridDim.x * blockDim.x;
  for (; i < n4; i += stride) dst[i] = src[i];
}

// ---------------- layernorm of rep rows ----------------
__global__ __launch_bounds__(256) void ln_kernel(const float* __restrict__ x,
                                                 const float* __restrict__ g,
                                                 const float* __restrict__ bvec,
                                                 float* __restrict__ h) {
  int m = blockIdx.x;                 // 0..4095 = b*N + n
  int b = m >> 11, n = m & 2047;
  int s = n >> 4, rl = n & 15;
  const float* row = x + ((size_t)((b * SS + s) * SEGC + rl)) * DD;
  int t = threadIdx.x;
  float v0 = row[t], v1 = row[t + 256], v2 = row[t + 512];
  float sum = v0 + v1 + v2;
  float sq = v0 * v0 + v1 * v1 + v2 * v2;
  __shared__ float rs[4], rq[4];
#pragma unroll
  for (int o = 32; o; o >>= 1) {
    sum += __shfl_down(sum, o);
    sq += __shfl_down(sq, o);
  }
  if ((t & 63) == 0) { rs[t >> 6] = sum; rq[t >> 6] = sq; }
  __syncthreads();
  sum = rs[0] + rs[1] + rs[2] + rs[3];
  sq = rq[0] + rq[1] + rq[2] + rq[3];
  float mu = sum * (1.f / 768.f);
  float var = sq * (1.f / 768.f) - mu * mu;
  float inv = rsqrtf(var + 1e-5f);
  float* hrow = h + (size_t)m * DD;
  hrow[t] = (v0 - mu) * inv * g[t] + bvec[t];
  hrow[t + 256] = (v1 - mu) * inv * g[t + 256] + bvec[t + 256];
  hrow[t + 512] = (v2 - mu) * inv * g[t + 512] + bvec[t + 512];
}

// ---------------- generic fp32 GEMM: C = alpha * A(MxK) @ B(KxN) ----------------
// K % 16 == 0, N % 64 == 0; M may be ragged (guarded).
__global__ __launch_bounds__(256) void gemm_nn(const float* __restrict__ A,
                                               const float* __restrict__ Bw,
                                               float* __restrict__ C, int M, int Nn,
                                               int K, float alpha) {
  __shared__ float As[16][68];
  __shared__ float Bs[16][68];
  int t = threadIdx.x;
  int tx = t & 15, ty = t >> 4;
  int row0 = blockIdx.y << 6, col0 = blockIdx.x << 6;
  float acc[4][4] = {{0.f}};
  int ar = t >> 2, ac = (t & 3) << 2;
  int br = t >> 4, bc = (t & 15) << 2;
  for (int k0 = 0; k0 < K; k0 += 16) {
    float4 av = make_float4(0.f, 0.f, 0.f, 0.f);
    if (row0 + ar < M) av = *(const float4*)(A + (size_t)(row0 + ar) * K + k0 + ac);
    As[ac + 0][ar] = av.x; As[ac + 1][ar] = av.y;
    As[ac + 2][ar] = av.z; As[ac + 3][ar] = av.w;
    float4 bv = *(const float4*)(Bw + (size_t)(k0 + br) * Nn + col0 + bc);
    *(float4*)&Bs[br][bc] = bv;
    __syncthreads();
#pragma unroll
    for (int kk = 0; kk < 16; ++kk) {
      float4 a = *(const float4*)&As[kk][ty << 2];
      float4 b = *(const float4*)&Bs[kk][tx << 2];
      float arr[4] = {a.x, a.y, a.z, a.w};
      float brr[4] = {b.x, b.y, b.z, b.w};
#pragma unroll
      for (int i = 0; i < 4; ++i)
#pragma unroll
        for (int j = 0; j < 4; ++j) acc[i][j] += arr[i] * brr[j];
    }
    __syncthreads();
  }
#pragma unroll
  for (int i = 0; i < 4; ++i) {
    int r = row0 + (ty << 2) + i;
    if (r < M) {
#pragma unroll
      for (int j = 0; j < 4; ++j)
        C[(size_t)r * Nn + col0 + (tx << 2) + j] = alpha * acc[i][j];
    }
  }
}

// ---------------- final GEMM: out = x + ao@Wo + bo (scattered into rep slots) ----
__global__ __launch_bounds__(256) void gemm_out(const float* __restrict__ A,
                                                const float* __restrict__ Bw,
                                                const float* __restrict__ x,
                                                const float* __restrict__ bo,
                                                float* __restrict__ out) {
  const int Nn = HDV, K = DD;  // 768, 768
  __shared__ float As[16][68];
  __shared__ float Bs[16][68];
  int t = threadIdx.x;
  int tx = t & 15, ty = t >> 4;
  int row0 = blockIdx.y << 6, col0 = blockIdx.x << 6;
  float acc[4][4] = {{0.f}};
  int ar = t >> 2, ac = (t & 3) << 2;
  int br = t >> 4, bc = (t & 15) << 2;
  for (int k0 = 0; k0 < K; k0 += 16) {
    float4 av = *(const float4*)(A + (size_t)(row0 + ar) * K + k0 + ac);
    As[ac + 0][ar] = av.x; As[ac + 1][ar] = av.y;
    As[ac + 2][ar] = av.z; As[ac + 3][ar] = av.w;
    float4 bv = *(const float4*)(Bw + (size_t)(k0 + br) * Nn + col0 + bc);
    *(float4*)&Bs[br][bc] = bv;
    __syncthreads();
#pragma unroll
    for (int kk = 0; kk < 16; ++kk) {
      float4 a = *(const float4*)&As[kk][ty << 2];
      float4 b = *(const float4*)&Bs[kk][tx << 2];
      float arr[4] = {a.x, a.y, a.z, a.w};
      float brr[4] = {b.x, b.y, b.z, b.w};
#pragma unroll
      for (int i = 0; i < 4; ++i)
#pragma unroll
        for (int j = 0; j < 4; ++j) acc[i][j] += arr[i] * brr[j];
    }
    __syncthreads();
  }
#pragma unroll
  for (int i = 0; i < 4; ++i) {
    int m = row0 + (ty << 2) + i;          // 0..4095
    int b = m >> 11, n = m & 2047;
    int s = n >> 4, rl = n & 15;
    size_t base = ((size_t)((b * SS + s) * SEGC + rl)) * DD;
#pragma unroll
    for (int j = 0; j < 4; ++j) {
      int col = col0 + (tx << 2) + j;
      out[base + col] = x[base + col] + acc[i][j] + bo[col];
    }
  }
}

// ---------------- flash-style attention ----------------
// grid: (64 q-tiles, H, B); 256 threads. TQ=32, TJ=32.
// logits[i,j] = (q_i+rwb)·k_j + (q_i+rrb)·relk[N-1+j-i]
__global__ __launch_bounds__(256) void attn_kernel(
    const float* __restrict__ q, const float* __restrict__ kk_,
    const float* __restrict__ vv_, const float* __restrict__ rkm,
    const float* __restrict__ rwb, const float* __restrict__ rrb,
    float* __restrict__ ao) {
  const int qt = blockIdx.x, hh = blockIdx.y, b = blockIdx.z;
  const int i0 = qt << 5;
  const int t = threadIdx.x;
  const int lane = t & 63, w = t >> 6;
  const int half = lane >> 5, jj = lane & 31;
  const int row8 = t >> 3, g = t & 7;   // softmax/PV mapping: row row8, 8 lanes each

  __shared__ float qw_s[32][64];        // q + r_w_bias
  __shared__ float qr_s[32][64];        // q + r_r_bias
  __shared__ float kt_s[32][65];
  __shared__ float rk_s[64][65];        // 63 rows used: li = jj - ii + 31 in [0,62]
  __shared__ float v_s[32][96];
  __shared__ float p_s[32][33];

  // stage q tiles once
  for (int u = t; u < 32 * 16; u += 256) {
    int r = u >> 4, c = (u & 15) << 2;
    const float* qrow = q + ((size_t)(b * NN + i0 + r)) * HDK + hh * DKC;
    float4 qv = *(const float4*)(qrow + c);
    float4 wv = *(const float4*)(rwb + hh * DKC + c);
    float4 rv = *(const float4*)(rrb + hh * DKC + c);
    qw_s[r][c + 0] = qv.x + wv.x; qw_s[r][c + 1] = qv.y + wv.y;
    qw_s[r][c + 2] = qv.z + wv.z; qw_s[r][c + 3] = qv.w + wv.w;
    qr_s[r][c + 0] = qv.x + rv.x; qr_s[r][c + 1] = qv.y + rv.y;
    qr_s[r][c + 2] = qv.z + rv.z; qr_s[r][c + 3] = qv.w + rv.w;
  }

  float m_i = -1e30f, l_i = 0.f;
  float acc[12];
#pragma unroll
  for (int c = 0; c < 12; ++c) acc[c] = 0.f;

  for (int j0 = 0; j0 < NN; j0 += 32) {
    // ---- stage K tile (32 x 64) ----
    for (int u = t; u < 32 * 16; u += 256) {
      int r = u >> 4, c = (u & 15) << 2;
      float4 kv = *(const float4*)(kk_ + ((size_t)(b * NN + j0 + r)) * HDK + hh * DKC + c);
      kt_s[r][c + 0] = kv.x; kt_s[r][c + 1] = kv.y;
      kt_s[r][c + 2] = kv.z; kt_s[r][c + 3] = kv.w;
    }
    // ---- stage rel_k tile (63 x 64), rows rb..rb+62, always in [0,4094] ----
    int rb = (NN - 1) + j0 - i0 - 31;
    for (int u = t; u < 63 * 16; u += 256) {
      int r = u >> 4, c = (u & 15) << 2;
      float4 rv = *(const float4*)(rkm + ((size_t)(rb + r)) * HDK + hh * DKC + c);
      rk_s[r][c + 0] = rv.x; rk_s[r][c + 1] = rv.y;
      rk_s[r][c + 2] = rv.z; rk_s[r][c + 3] = rv.w;
    }
    // ---- stage V tile (32 x 96) ----
    for (int u = t; u < 32 * 24; u += 256) {
      int r = u / 24, c = (u % 24) << 2;
      float4 vv = *(const float4*)(vv_ + ((size_t)(b * NN + j0 + r)) * HDV + hh * DVC + c);
      *(float4*)&v_s[r][c] = vv;
    }
    __syncthreads();

    // ---- scores: wave w covers rows [8w,8w+8); per u, 2 rows x 32 cols ----
#pragma unroll
    for (int u = 0; u < 4; ++u) {
      int ii = (w << 3) + (u << 1) + half;
      int li = jj - ii + 31;
      float sc = 0.f;
#pragma unroll
      for (int d = 0; d < 64; d += 4) {
        float4 qa = *(const float4*)&qw_s[ii][d];
        float4 qb = *(const float4*)&qr_s[ii][d];
        sc += qa.x * kt_s[jj][d + 0] + qb.x * rk_s[li][d + 0];
        sc += qa.y * kt_s[jj][d + 1] + qb.y * rk_s[li][d + 1];
        sc += qa.z * kt_s[jj][d + 2] + qb.z * rk_s[li][d + 2];
        sc += qa.w * kt_s[jj][d + 3] + qb.w * rk_s[li][d + 3];
      }
      p_s[ii][jj] = sc;
    }
    // p_s rows [8w,8w+8) written and read by the same wave: wave-coherent, no barrier.

    // ---- online softmax update (thread: row row8, lane-group g) ----
    float mx = -1e30f;
#pragma unroll
    for (int j2 = 0; j2 < 4; ++j2) mx = fmaxf(mx, p_s[row8][(j2 << 3) + g]);
    mx = fmaxf(mx, __shfl_xor(mx, 1));
    mx = fmaxf(mx, __shfl_xor(mx, 2));
    mx = fmaxf(mx, __shfl_xor(mx, 4));
    float m_new = fmaxf(m_i, mx);
    float al = __expf(m_i - m_new);
    float sm = 0.f;
#pragma unroll
    for (int j2 = 0; j2 < 4; ++j2) {
      int j = (j2 << 3) + g;
      float p = __expf(p_s[row8][j] - m_new);
      p_s[row8][j] = p;
      sm += p;
    }
    sm += __shfl_xor(sm, 1);
    sm += __shfl_xor(sm, 2);
    sm += __shfl_xor(sm, 4);
    l_i = l_i * al + sm;
    m_i = m_new;
#pragma unroll
    for (int c = 0; c < 12; ++c) acc[c] *= al;

    // ---- PV: acc[row8][g*12 + c] += p * v ----
#pragma unroll 8
    for (int j = 0; j < 32; ++j) {
      float pj = p_s[row8][j];
      const float* vr = &v_s[j][g * 12];
#pragma unroll
      for (int c = 0; c < 12; ++c) acc[c] += pj * vr[c];
    }
    __syncthreads();
  }

  float invl = 1.f / l_i;
  float* orow = ao + ((size_t)(b * NN + i0 + row8)) * HDV + hh * DVC + g * 12;
#pragma unroll
  for (int c = 0; c < 12; ++c) orow[c] = acc[c] * invl;
}

// ---------------- launch ----------------
extern "C" void kernel_launch(void* const* d_in, const int* in_sizes, int n_in,
                              void* d_out, int out_size, void* d_ws, size_t ws_size,
                              hipStream_t stream) {
  (void)in_sizes; (void)n_in; (void)out_size; (void)ws_size;
  const float* x = (const float*)d_in[0];
  const float* ln_g = (const float*)d_in[1];
  const float* ln_b = (const float*)d_in[2];
  const float* Wq = (const float*)d_in[3];
  const float* Wk = (const float*)d_in[4];
  const float* Wv = (const float*)d_in[5];
  const float* Wr = (const float*)d_in[6];
  const float* rwb = (const float*)d_in[7];
  const float* rrb = (const float*)d_in[8];
  const float* Wo = (const float*)d_in[9];
  const float* bo = (const float*)d_in[10];
  const float* pe = (const float*)d_in[11];
  float* out = (float*)d_out;

  // ws layout (fp32): ~60 MB total
  float* ws = (float*)d_ws;
  float* h = ws;                 ws += (size_t)4096 * 768;
  float* qb = ws;                ws += (size_t)4096 * 512;
  float* kb = ws;                ws += (size_t)4096 * 512;
  float* vb = ws;                ws += (size_t)4096 * 768;
  float* rk = ws;                ws += (size_t)4095 * 512;
  float* ao = ws;

  copy4<<<dim3(2048), dim3(256), 0, stream>>>((const float4*)x, (float4*)out, 6291456);
  ln_kernel<<<dim3(4096), dim3(256), 0, stream>>>(x, ln_g, ln_b, h);
  gemm_nn<<<dim3(8, 64), dim3(256), 0, stream>>>(h, Wq, qb, 4096, 512, 768, 0.125f);
  gemm_nn<<<dim3(8, 64), dim3(256), 0, stream>>>(h, Wk, kb, 4096, 512, 768, 1.f);
  gemm_nn<<<dim3(12, 64), dim3(256), 0, stream>>>(h, Wv, vb, 4096, 768, 768, 1.f);
  gemm_nn<<<dim3(8, 64), dim3(256), 0, stream>>>(pe, Wr, rk, 4095, 512, 96, 1.f);
  attn_kernel<<<dim3(64, 8, 2), dim3(256), 0, stream>>>(qb, kb, vb, rk, rwb, rrb, ao);
  gemm_out<<<dim3(12, 64), dim3(256), 0, stream>>>(ao, Wo, x, bo, out);
}

// Round 2
// 710.248 us; speedup vs baseline: 4.8996x; 4.8996x over previous
//
#include <hip/hip_runtime.h>

typedef short s8v __attribute__((ext_vector_type(8)));
typedef float f4 __attribute__((ext_vector_type(4)));

__device__ inline float bf2f(unsigned short u) {
  union { unsigned i; float f; } x; x.i = (unsigned)u << 16; return x.f;
}
__device__ inline unsigned short f2bf(float f) {
  union { float f; unsigned i; } x; x.f = f;
  return (unsigned short)((x.i + 0x7fffu + ((x.i >> 16) & 1u)) >> 16);
}

// ---------------- copy x -> out ----------------
__global__ __launch_bounds__(256) void copy4(const float4* __restrict__ src,
                                             float4* __restrict__ dst, int n4) {
  int i = blockIdx.x * blockDim.x + threadIdx.x;
  int stride = gridDim.x * blockDim.x;
  for (; i < n4; i += stride) dst[i] = src[i];
}

// ---------------- layernorm of rep rows ----------------
__global__ __launch_bounds__(256) void ln_kernel(const float* __restrict__ x,
                                                 const float* __restrict__ g,
                                                 const float* __restrict__ bvec,
                                                 float* __restrict__ h) {
  int m = blockIdx.x;                 // 0..4095 = b*N + n
  int b = m >> 11, n = m & 2047;
  int s = n >> 4, rl = n & 15;
  const float* row = x + ((size_t)((b * 128 + s) * 128 + rl)) * 768;
  int t = threadIdx.x;
  float v0 = row[t], v1 = row[t + 256], v2 = row[t + 512];
  float sum = v0 + v1 + v2;
  float sq = v0 * v0 + v1 * v1 + v2 * v2;
  __shared__ float rs[4], rq[4];
#pragma unroll
  for (int o = 32; o; o >>= 1) {
    sum += __shfl_down(sum, o);
    sq += __shfl_down(sq, o);
  }
  if ((t & 63) == 0) { rs[t >> 6] = sum; rq[t >> 6] = sq; }
  __syncthreads();
  sum = rs[0] + rs[1] + rs[2] + rs[3];
  sq = rq[0] + rq[1] + rq[2] + rq[3];
  float mu = sum * (1.f / 768.f);
  float var = sq * (1.f / 768.f) - mu * mu;
  float inv = rsqrtf(var + 1e-5f);
  float* hrow = h + (size_t)m * 768;
  hrow[t] = (v0 - mu) * inv * g[t] + bvec[t];
  hrow[t + 256] = (v1 - mu) * inv * g[t + 256] + bvec[t + 256];
  hrow[t + 512] = (v2 - mu) * inv * g[t + 512] + bvec[t + 512];
}

// ---------------- fp32 GEMM with bf16 epilogues ----------------
// MODE 1: bf16 row-major -> C0
// MODE 2: qw/qr pair: C0 = alpha*acc + b0[col], C1 = alpha*acc + b1[col]
// MODE 3: V transposed: C0[((b*768 + col) << 11) + j], row m = b*2048 + j
template <int MODE>
__global__ __launch_bounds__(256) void gemm_nn(const float* __restrict__ A,
                                               const float* __restrict__ Bw,
                                               unsigned short* __restrict__ C0,
                                               unsigned short* __restrict__ C1,
                                               const float* __restrict__ b0,
                                               const float* __restrict__ b1,
                                               int M, int Nn, int K, float alpha) {
  __shared__ float As[16][68];
  __shared__ float Bs[16][68];
  int t = threadIdx.x;
  int tx = t & 15, ty = t >> 4;
  int row0 = blockIdx.y << 6, col0 = blockIdx.x << 6;
  float acc[4][4] = {{0.f}};
  int ar = t >> 2, ac = (t & 3) << 2;
  int br = t >> 4, bc = (t & 15) << 2;
  for (int k0 = 0; k0 < K; k0 += 16) {
    float4 av = make_float4(0.f, 0.f, 0.f, 0.f);
    if (row0 + ar < M) av = *(const float4*)(A + (size_t)(row0 + ar) * K + k0 + ac);
    As[ac + 0][ar] = av.x; As[ac + 1][ar] = av.y;
    As[ac + 2][ar] = av.z; As[ac + 3][ar] = av.w;
    float4 bv = *(const float4*)(Bw + (size_t)(k0 + br) * Nn + col0 + bc);
    *(float4*)&Bs[br][bc] = bv;
    __syncthreads();
#pragma unroll
    for (int kk = 0; kk < 16; ++kk) {
      float4 a = *(const float4*)&As[kk][ty << 2];
      float4 b = *(const float4*)&Bs[kk][tx << 2];
      float arr[4] = {a.x, a.y, a.z, a.w};
      float brr[4] = {b.x, b.y, b.z, b.w};
#pragma unroll
      for (int i = 0; i < 4; ++i)
#pragma unroll
        for (int j = 0; j < 4; ++j) acc[i][j] += arr[i] * brr[j];
    }
    __syncthreads();
  }
#pragma unroll
  for (int i = 0; i < 4; ++i) {
    int r = row0 + (ty << 2) + i;
    if (r >= M) continue;
    int colb = col0 + (tx << 2);
    if (MODE == 1) {
      unsigned pk0 = f2bf(alpha * acc[i][0]) | ((unsigned)f2bf(alpha * acc[i][1]) << 16);
      unsigned pk1 = f2bf(alpha * acc[i][2]) | ((unsigned)f2bf(alpha * acc[i][3]) << 16);
      uint2 pk = make_uint2(pk0, pk1);
      *(uint2*)(C0 + (size_t)r * Nn + colb) = pk;
    } else if (MODE == 2) {
#pragma unroll
      for (int j = 0; j < 4; ++j) {
        float v = alpha * acc[i][j];
        C0[(size_t)r * Nn + colb + j] = f2bf(v + b0[colb + j]);
        C1[(size_t)r * Nn + colb + j] = f2bf(v + b1[colb + j]);
      }
    } else {  // MODE 3
      int bb = r >> 11, j_ = r & 2047;
#pragma unroll
      for (int j = 0; j < 4; ++j) {
        int col = colb + j;
        C0[(((size_t)(bb * 768 + col)) << 11) + j_] = f2bf(alpha * acc[i][j]);
      }
    }
  }
}

// ---------------- final GEMM: out = x + ao@Wo + bo (A is bf16) ----------------
__global__ __launch_bounds__(256) void gemm_out(const unsigned short* __restrict__ A,
                                                const float* __restrict__ Bw,
                                                const float* __restrict__ x,
                                                const float* __restrict__ bo,
                                                float* __restrict__ out) {
  const int Nn = 768, K = 768;
  __shared__ float As[16][68];
  __shared__ float Bs[16][68];
  int t = threadIdx.x;
  int tx = t & 15, ty = t >> 4;
  int row0 = blockIdx.y << 6, col0 = blockIdx.x << 6;
  float acc[4][4] = {{0.f}};
  int ar = t >> 2, ac = (t & 3) << 2;
  int br = t >> 4, bc = (t & 15) << 2;
  for (int k0 = 0; k0 < K; k0 += 16) {
    ushort4 av = *(const ushort4*)(A + (size_t)(row0 + ar) * K + k0 + ac);
    As[ac + 0][ar] = bf2f(av.x); As[ac + 1][ar] = bf2f(av.y);
    As[ac + 2][ar] = bf2f(av.z); As[ac + 3][ar] = bf2f(av.w);
    float4 bv = *(const float4*)(Bw + (size_t)(k0 + br) * Nn + col0 + bc);
    *(float4*)&Bs[br][bc] = bv;
    __syncthreads();
#pragma unroll
    for (int kk = 0; kk < 16; ++kk) {
      float4 a = *(const float4*)&As[kk][ty << 2];
      float4 b = *(const float4*)&Bs[kk][tx << 2];
      float arr[4] = {a.x, a.y, a.z, a.w};
      float brr[4] = {b.x, b.y, b.z, b.w};
#pragma unroll
      for (int i = 0; i < 4; ++i)
#pragma unroll
        for (int j = 0; j < 4; ++j) acc[i][j] += arr[i] * brr[j];
    }
    __syncthreads();
  }
#pragma unroll
  for (int i = 0; i < 4; ++i) {
    int m = row0 + (ty << 2) + i;
    int b = m >> 11, n = m & 2047;
    int s = n >> 4, rl = n & 15;
    size_t base = ((size_t)((b * 128 + s) * 128 + rl)) * 768;
#pragma unroll
    for (int j = 0; j < 4; ++j) {
      int col = col0 + (tx << 2) + j;
      out[base + col] = x[base + col] + acc[i][j] + bo[col];
    }
  }
}

// ---------------- MFMA flash attention ----------------
// grid (64 q-tiles, 8 heads, 2 batch), 256 threads (4 waves).
// TQ=32, TJ=64. logits[i,j] = qw_i·k_j + qr_i·rk[2047+j-i]
__global__ __launch_bounds__(256) void attn_kernel(
    const unsigned short* __restrict__ qw_g, const unsigned short* __restrict__ qr_g,
    const unsigned short* __restrict__ k_g, const unsigned short* __restrict__ vt_g,
    const unsigned short* __restrict__ rk_g, unsigned short* __restrict__ ao) {
  const int qt = blockIdx.x, hh = blockIdx.y, b = blockIdx.z;
  const int i0 = qt << 5;
  const int t = threadIdx.x;
  const int lane = t & 63, w = t >> 6;
  const int m16 = lane & 15, quad = lane >> 4;
  const int mi = w & 1, njb = w >> 1;
  const int sr = t >> 3, sg = t & 7;   // softmax role: row sr, 8 lanes/row

  __shared__ __align__(16) short qw_s[32 * 64];
  __shared__ __align__(16) short qr_s[32 * 64];
  __shared__ __align__(16) short k_s[64 * 64];
  __shared__ __align__(16) short rk_s[96 * 64];
  __shared__ __align__(16) short vt_s[96 * 64];
  __shared__ __align__(16) short pb_s[32 * 64];
  __shared__ float p_s[32][68];
  __shared__ short t_s[32][104];
  __shared__ float alpha_s[32];
  __shared__ float linv_s[32];

  // stage Q (both bias variants), XOR-swizzled 16B chunks
  for (int u = t; u < 512; u += 256) {
    int tile = u >> 8, idx = u & 255, r = idx >> 3, ch = idx & 7;
    const unsigned short* src =
        (tile ? qr_g : qw_g) + (((size_t)(b * 2048 + i0 + r)) << 9) + (hh << 6) + (ch << 3);
    int4 vdat = *(const int4*)src;
    short* dst = (tile ? qr_s : qw_s) + r * 64 + (((ch ^ (r & 7))) << 3);
    *(int4*)dst = vdat;
  }

  float m_i = -1e30f, l_i = 0.f;
  f4 o0 = {0.f, 0.f, 0.f, 0.f}, o1 = o0, o2 = o0;
  const int arow = mi * 16 + m16;
  const int asw = arow & 7;
  const int crow = mi * 16 + quad * 4;
  const int brow0 = njb * 16 + m16;
  const int bsw = brow0 & 7;

  for (int j0 = 0; j0 < 2048; j0 += 64) {
    __syncthreads();
    // stage K (64x64)
    for (int u = t; u < 512; u += 256) {
      int r = u >> 3, ch = u & 7;
      int4 vdat = *(const int4*)(k_g + (((size_t)(b * 2048 + j0 + r)) << 9) + (hh << 6) + (ch << 3));
      *(int4*)(k_s + r * 64 + ((ch ^ (r & 7)) << 3)) = vdat;
    }
    // stage rel_k band: rows rbase..rbase+94 (all in [0,4094])
    int rbase = 2047 + j0 - i0 - 31;
    for (int u = t; u < 760; u += 256) {
      int r = u >> 3, ch = u & 7;
      int4 vdat = *(const int4*)(rk_g + (((size_t)(rbase + r)) << 9) + (hh << 6) + (ch << 3));
      *(int4*)(rk_s + r * 64 + ((ch ^ (r & 7)) << 3)) = vdat;
    }
    // stage V^T (96 value-dims x 64 j)
    for (int u = t; u < 768; u += 256) {
      int r = u >> 3, ch = u & 7;
      int4 vdat =
          *(const int4*)(vt_g + (((size_t)(b * 768 + hh * 96 + r)) << 11) + j0 + (ch << 3));
      *(int4*)(vt_s + r * 64 + ((ch ^ (r & 7)) << 3)) = vdat;
    }
    __syncthreads();

    // ---- content QK^T (2 tiles/wave) + rel band (3 tiles/wave) ----
    f4 c0 = {0.f, 0.f, 0.f, 0.f}, c1 = c0;
    f4 r0 = c0, r1 = c0, r2 = c0;
#pragma unroll
    for (int kb = 0; kb < 2; ++kb) {
      int co = ((kb * 4 + quad) ^ asw) << 3;
      int cb = ((kb * 4 + quad) ^ bsw) << 3;
      s8v aq = *(const s8v*)(qw_s + arow * 64 + co);
      s8v ar = *(const s8v*)(qr_s + arow * 64 + co);
      s8v bk0 = *(const s8v*)(k_s + brow0 * 64 + cb);
      s8v bk1 = *(const s8v*)(k_s + (brow0 + 32) * 64 + cb);
      c0 = __builtin_amdgcn_mfma_f32_16x16x32_bf16(aq, bk0, c0, 0, 0, 0);
      c1 = __builtin_amdgcn_mfma_f32_16x16x32_bf16(aq, bk1, c1, 0, 0, 0);
      s8v br0 = *(const s8v*)(rk_s + brow0 * 64 + cb);
      s8v br1 = *(const s8v*)(rk_s + (brow0 + 32) * 64 + cb);
      s8v br2 = *(const s8v*)(rk_s + (brow0 + 64) * 64 + cb);
      r0 = __builtin_amdgcn_mfma_f32_16x16x32_bf16(ar, br0, r0, 0, 0, 0);
      r1 = __builtin_amdgcn_mfma_f32_16x16x32_bf16(ar, br1, r1, 0, 0, 0);
      r2 = __builtin_amdgcn_mfma_f32_16x16x32_bf16(ar, br2, r2, 0, 0, 0);
    }
#pragma unroll
    for (int rr = 0; rr < 4; ++rr) {
      p_s[crow + rr][njb * 16 + m16] = c0[rr];
      p_s[crow + rr][(njb + 2) * 16 + m16] = c1[rr];
      t_s[crow + rr][njb * 16 + m16] = (short)f2bf(r0[rr]);
      t_s[crow + rr][(njb + 2) * 16 + m16] = (short)f2bf(r1[rr]);
      t_s[crow + rr][(njb + 4) * 16 + m16] = (short)f2bf(r2[rr]);
    }
    __syncthreads();

    // ---- online softmax over 64 cols ----
    float sv[8];
    float mx = -1e30f;
#pragma unroll
    for (int j2 = 0; j2 < 8; ++j2) {
      int c = sg + (j2 << 3);
      float s = p_s[sr][c] + bf2f((unsigned short)t_s[sr][c - sr + 31]);
      sv[j2] = s;
      mx = fmaxf(mx, s);
    }
    mx = fmaxf(mx, __shfl_xor(mx, 1));
    mx = fmaxf(mx, __shfl_xor(mx, 2));
    mx = fmaxf(mx, __shfl_xor(mx, 4));
    float m_new = fmaxf(m_i, mx);
    float al = __expf(m_i - m_new);
    float sm = 0.f;
#pragma unroll
    for (int j2 = 0; j2 < 8; ++j2) {
      float p = __expf(sv[j2] - m_new);
      sm += p;
      pb_s[sr * 64 + ((j2 ^ (sr & 7)) << 3) + sg] = (short)f2bf(p);
    }
    sm += __shfl_xor(sm, 1);
    sm += __shfl_xor(sm, 2);
    sm += __shfl_xor(sm, 4);
    l_i = l_i * al + sm;
    m_i = m_new;
    if (sg == 0) alpha_s[sr] = al;
    __syncthreads();

    // ---- rescale + PV (3 tiles/wave) ----
#pragma unroll
    for (int rr = 0; rr < 4; ++rr) {
      float a = alpha_s[crow + rr];
      o0[rr] *= a; o1[rr] *= a; o2[rr] *= a;
    }
#pragma unroll
    for (int kb = 0; kb < 2; ++kb) {
      int co = ((kb * 4 + quad) ^ asw) << 3;
      int cb = ((kb * 4 + quad) ^ bsw) << 3;
      s8v ap = *(const s8v*)(pb_s + arow * 64 + co);
      s8v b0v = *(const s8v*)(vt_s + brow0 * 64 + cb);
      s8v b1v = *(const s8v*)(vt_s + (brow0 + 32) * 64 + cb);
      s8v b2v = *(const s8v*)(vt_s + (brow0 + 64) * 64 + cb);
      o0 = __builtin_amdgcn_mfma_f32_16x16x32_bf16(ap, b0v, o0, 0, 0, 0);
      o1 = __builtin_amdgcn_mfma_f32_16x16x32_bf16(ap, b1v, o1, 0, 0, 0);
      o2 = __builtin_amdgcn_mfma_f32_16x16x32_bf16(ap, b2v, o2, 0, 0, 0);
    }
  }

  if (sg == 0) linv_s[sr] = 1.f / l_i;
  __syncthreads();
#pragma unroll
  for (int rr = 0; rr < 4; ++rr) {
    int row = crow + rr;
    float inv = linv_s[row];
    size_t gbase = ((size_t)(b * 2048 + i0 + row)) * 768 + hh * 96;
    ao[gbase + njb * 16 + m16] = f2bf(o0[rr] * inv);
    ao[gbase + (njb + 2) * 16 + m16] = f2bf(o1[rr] * inv);
    ao[gbase + (njb + 4) * 16 + m16] = f2bf(o2[rr] * inv);
  }
}

// ---------------- launch ----------------
extern "C" void kernel_launch(void* const* d_in, const int* in_sizes, int n_in,
                              void* d_out, int out_size, void* d_ws, size_t ws_size,
                              hipStream_t stream) {
  (void)in_sizes; (void)n_in; (void)out_size; (void)ws_size;
  const float* x = (const float*)d_in[0];
  const float* ln_g = (const float*)d_in[1];
  const float* ln_b = (const float*)d_in[2];
  const float* Wq = (const float*)d_in[3];
  const float* Wk = (const float*)d_in[4];
  const float* Wv = (const float*)d_in[5];
  const float* Wr = (const float*)d_in[6];
  const float* rwb = (const float*)d_in[7];
  const float* rrb = (const float*)d_in[8];
  const float* Wo = (const float*)d_in[9];
  const float* bo = (const float*)d_in[10];
  const float* pe = (const float*)d_in[11];
  float* out = (float*)d_out;

  char* p = (char*)d_ws;
  float* h = (float*)p;            p += (size_t)4096 * 768 * 4;
  unsigned short* qw = (unsigned short*)p; p += (size_t)4096 * 512 * 2;
  unsigned short* qr = (unsigned short*)p; p += (size_t)4096 * 512 * 2;
  unsigned short* kb = (unsigned short*)p; p += (size_t)4096 * 512 * 2;
  unsigned short* vt = (unsigned short*)p; p += (size_t)4096 * 768 * 2;
  unsigned short* rk = (unsigned short*)p; p += (size_t)4095 * 512 * 2;
  unsigned short* ao = (unsigned short*)p;

  copy4<<<dim3(2048), dim3(256), 0, stream>>>((const float4*)x, (float4*)out, 6291456);
  ln_kernel<<<dim3(4096), dim3(256), 0, stream>>>(x, ln_g, ln_b, h);
  gemm_nn<2><<<dim3(8, 64), dim3(256), 0, stream>>>(h, Wq, qw, qr, rwb, rrb, 4096, 512, 768, 0.125f);
  gemm_nn<1><<<dim3(8, 64), dim3(256), 0, stream>>>(h, Wk, kb, nullptr, nullptr, nullptr, 4096, 512, 768, 1.f);
  gemm_nn<3><<<dim3(12, 64), dim3(256), 0, stream>>>(h, Wv, vt, nullptr, nullptr, nullptr, 4096, 768, 768, 1.f);
  gemm_nn<1><<<dim3(8, 64), dim3(256), 0, stream>>>(pe, Wr, rk, nullptr, nullptr, nullptr, 4095, 512, 96, 1.f);
  attn_kernel<<<dim3(64, 8, 2), dim3(256), 0, stream>>>(qw, qr, kb, vt, rk, ao);
  gemm_out<<<dim3(12, 64), dim3(256), 0, stream>>>(ao, Wo, x, bo, out);
}

// Round 3
// 504.819 us; speedup vs baseline: 6.8934x; 1.4069x over previous
//
#include <hip/hip_runtime.h>

typedef short s8v __attribute__((ext_vector_type(8)));
typedef float f4 __attribute__((ext_vector_type(4)));

__device__ inline float bf2f(unsigned short u) {
  union { unsigned i; float f; } x; x.i = (unsigned)u << 16; return x.f;
}
__device__ inline unsigned short f2bf(float f) {
  union { float f; unsigned i; } x; x.f = f;
  return (unsigned short)((x.i + 0x7fffu + ((x.i >> 16) & 1u)) >> 16);
}

__device__ inline void gload16(const void* g, void* l) {
  __builtin_amdgcn_global_load_lds(
      (const __attribute__((address_space(1))) unsigned int*)g,
      (__attribute__((address_space(3))) unsigned int*)l, 16, 0, 0);
}

// ---------------- copy x -> out ----------------
__global__ __launch_bounds__(256) void copy4(const float4* __restrict__ src,
                                             float4* __restrict__ dst, int n4) {
  int i = blockIdx.x * blockDim.x + threadIdx.x;
  int stride = gridDim.x * blockDim.x;
  for (; i < n4; i += stride) dst[i] = src[i];
}

// ---------------- layernorm of rep rows -> bf16 h ----------------
__global__ __launch_bounds__(256) void ln_kernel(const float* __restrict__ x,
                                                 const float* __restrict__ g,
                                                 const float* __restrict__ bvec,
                                                 unsigned short* __restrict__ h) {
  int m = blockIdx.x;                 // 0..4095 = b*N + n
  int b = m >> 11, n = m & 2047;
  int s = n >> 4, rl = n & 15;
  const float* row = x + ((size_t)((b * 128 + s) * 128 + rl)) * 768;
  int t = threadIdx.x;
  float v0 = row[t], v1 = row[t + 256], v2 = row[t + 512];
  float sum = v0 + v1 + v2;
  float sq = v0 * v0 + v1 * v1 + v2 * v2;
  __shared__ float rs[4], rq[4];
#pragma unroll
  for (int o = 32; o; o >>= 1) {
    sum += __shfl_down(sum, o);
    sq += __shfl_down(sq, o);
  }
  if ((t & 63) == 0) { rs[t >> 6] = sum; rq[t >> 6] = sq; }
  __syncthreads();
  sum = rs[0] + rs[1] + rs[2] + rs[3];
  sq = rq[0] + rq[1] + rq[2] + rq[3];
  float mu = sum * (1.f / 768.f);
  float var = sq * (1.f / 768.f) - mu * mu;
  float inv = rsqrtf(var + 1e-5f);
  unsigned short* hrow = h + (size_t)m * 768;
  hrow[t] = f2bf((v0 - mu) * inv * g[t] + bvec[t]);
  hrow[t + 256] = f2bf((v1 - mu) * inv * g[t + 256] + bvec[t + 256]);
  hrow[t + 512] = f2bf((v2 - mu) * inv * g[t + 512] + bvec[t + 512]);
}

// ---------------- weight transpose + bf16 convert ----------------
// dst[n][k] = src[k][n]; K=768 fixed.
__global__ __launch_bounds__(256) void transp_cvt(const float* __restrict__ Wq,
                                                  const float* __restrict__ Wk,
                                                  const float* __restrict__ Wv,
                                                  const float* __restrict__ Wo,
                                                  unsigned short* __restrict__ Bt,
                                                  unsigned short* __restrict__ Bto) {
  int z = blockIdx.z;
  const float* src; unsigned short* dst; int N;
  if (z == 0) { src = Wq; dst = Bt; N = 512; }
  else if (z == 1) { src = Wk; dst = Bt + (size_t)512 * 768; N = 512; }
  else if (z == 2) { src = Wv; dst = Bt + (size_t)1024 * 768; N = 768; }
  else { src = Wo; dst = Bto; N = 768; }
  int n0 = blockIdx.x << 6, k0 = blockIdx.y << 6;
  if (n0 >= N) return;
  __shared__ float tile[64][65];
  int t = threadIdx.x;
  int c4 = (t & 15) << 2, rr = t >> 4;
#pragma unroll
  for (int i = 0; i < 4; ++i) {
    int kr = rr + (i << 4);
    float4 v = *(const float4*)(src + (size_t)(k0 + kr) * N + n0 + c4);
    tile[c4 + 0][kr] = v.x; tile[c4 + 1][kr] = v.y;
    tile[c4 + 2][kr] = v.z; tile[c4 + 3][kr] = v.w;
  }
  __syncthreads();
  int rowN = t >> 2, kc = (t & 3) << 4;
#pragma unroll
  for (int j = 0; j < 16; ++j)
    dst[(size_t)(n0 + rowN) * 768 + k0 + kc + j] = f2bf(tile[rowN][kc + j]);
}

// ---------------- rel_k GEMM (small, fp32 in, bf16 out) ----------------
// C = A(M x K) @ B(K x N), M=4095, N=512, K=96
__global__ __launch_bounds__(256) void gemm_rel(const float* __restrict__ A,
                                                const float* __restrict__ Bw,
                                                unsigned short* __restrict__ C0,
                                                int M, int Nn, int K) {
  __shared__ float As[16][68];
  __shared__ float Bs[16][68];
  int t = threadIdx.x;
  int tx = t & 15, ty = t >> 4;
  int row0 = blockIdx.y << 6, col0 = blockIdx.x << 6;
  float acc[4][4] = {{0.f}};
  int ar = t >> 2, ac = (t & 3) << 2;
  int br = t >> 4, bc = (t & 15) << 2;
  for (int k0 = 0; k0 < K; k0 += 16) {
    float4 av = make_float4(0.f, 0.f, 0.f, 0.f);
    if (row0 + ar < M) av = *(const float4*)(A + (size_t)(row0 + ar) * K + k0 + ac);
    As[ac + 0][ar] = av.x; As[ac + 1][ar] = av.y;
    As[ac + 2][ar] = av.z; As[ac + 3][ar] = av.w;
    float4 bv = *(const float4*)(Bw + (size_t)(k0 + br) * Nn + col0 + bc);
    *(float4*)&Bs[br][bc] = bv;
    __syncthreads();
#pragma unroll
    for (int kk = 0; kk < 16; ++kk) {
      float4 a = *(const float4*)&As[kk][ty << 2];
      float4 b = *(const float4*)&Bs[kk][tx << 2];
      float arr[4] = {a.x, a.y, a.z, a.w};
      float brr[4] = {b.x, b.y, b.z, b.w};
#pragma unroll
      for (int i = 0; i < 4; ++i)
#pragma unroll
        for (int j = 0; j < 4; ++j) acc[i][j] += arr[i] * brr[j];
    }
    __syncthreads();
  }
#pragma unroll
  for (int i = 0; i < 4; ++i) {
    int r = row0 + (ty << 2) + i;
    if (r >= M) continue;
    int colb = col0 + (tx << 2);
    unsigned pk0 = f2bf(acc[i][0]) | ((unsigned)f2bf(acc[i][1]) << 16);
    unsigned pk1 = f2bf(acc[i][2]) | ((unsigned)f2bf(acc[i][3]) << 16);
    *(uint2*)(C0 + (size_t)r * Nn + colb) = make_uint2(pk0, pk1);
  }
}

// ---------------- MFMA GEMM (m97 structure): C = A(Mx768) @ Bt^T ----------------
// A bf16 row-major (K=768 contiguous), Bt bf16 N x 768 row-major.
// MODE 0: fused QKV epilogue (N=1792: q|k|v). MODE 1: out epilogue (N=768).
template <int MODE>
__global__ __launch_bounds__(256) void gemm_mfma(
    const unsigned short* __restrict__ A, const unsigned short* __restrict__ Bt,
    unsigned short* __restrict__ qw, unsigned short* __restrict__ qr,
    unsigned short* __restrict__ kbuf, unsigned short* __restrict__ vt,
    const float* __restrict__ rwb, const float* __restrict__ rrb,
    const float* __restrict__ x, const float* __restrict__ bo,
    float* __restrict__ out) {
  __shared__ __align__(16) short As[128 * 64];
  __shared__ __align__(16) short Bs[128 * 64];
  const int t = threadIdx.x;
  const int w = t >> 6, lane = t & 63;
  const int m16 = lane & 15, quad = lane >> 4;
  const int wm = w >> 1, wn = w & 1;
  const int m0 = blockIdx.y << 7, n0 = blockIdx.x << 7;
  const int K = 768;

  f4 acc[4][4];
#pragma unroll
  for (int i = 0; i < 4; ++i)
#pragma unroll
    for (int j = 0; j < 4; ++j) acc[i][j] = (f4){0.f, 0.f, 0.f, 0.f};

  const int rA = lane >> 3;   // row-within-segment
  const int cA = lane & 7;    // chunk slot

  for (int k0 = 0; k0 < K; k0 += 64) {
    __syncthreads();
#pragma unroll
    for (int i = 0; i < 4; ++i) {
      int seg = (w << 2) + i;            // 16 segments of 64 slots
      int r = (seg << 3) + rA;           // tile row 0..127
      int cg = cA ^ (r & 7);             // global chunk for this slot
      gload16(A + (size_t)(m0 + r) * K + k0 + (cg << 3), (short*)As + (seg << 9));
      gload16(Bt + (size_t)(n0 + r) * K + k0 + (cg << 3), (short*)Bs + (seg << 9));
    }
    __syncthreads();
#pragma unroll
    for (int kb = 0; kb < 2; ++kb) {
      int cs = ((kb << 2) + quad) ^ (m16 & 7);
      s8v af[4], bf[4];
#pragma unroll
      for (int mt = 0; mt < 4; ++mt) {
        int r = (wm << 6) + (mt << 4) + m16;
        af[mt] = *(const s8v*)(As + (r << 6) + (cs << 3));
      }
#pragma unroll
      for (int nt = 0; nt < 4; ++nt) {
        int rn = (wn << 6) + (nt << 4) + m16;
        bf[nt] = *(const s8v*)(Bs + (rn << 6) + (cs << 3));
      }
#pragma unroll
      for (int mt = 0; mt < 4; ++mt)
#pragma unroll
        for (int nt = 0; nt < 4; ++nt)
          acc[mt][nt] = __builtin_amdgcn_mfma_f32_16x16x32_bf16(af[mt], bf[nt], acc[mt][nt], 0, 0, 0);
    }
  }

#pragma unroll
  for (int nt = 0; nt < 4; ++nt) {
    int n = n0 + (wn << 6) + (nt << 4) + m16;
#pragma unroll
    for (int mt = 0; mt < 4; ++mt) {
#pragma unroll
      for (int rr = 0; rr < 4; ++rr) {
        int m = m0 + (wm << 6) + (mt << 4) + (quad << 2) + rr;
        float v = acc[mt][nt][rr];
        if (MODE == 0) {
          if (n < 512) {
            float vs = v * 0.125f;
            qw[(size_t)m * 512 + n] = f2bf(vs + rwb[n]);
            qr[(size_t)m * 512 + n] = f2bf(vs + rrb[n]);
          } else if (n < 1024) {
            kbuf[(size_t)m * 512 + (n - 512)] = f2bf(v);
          } else {
            int col = n - 1024;
            int b = m >> 11, j = m & 2047;
            vt[(((size_t)(b * 768 + col)) << 11) + j] = f2bf(v);
          }
        } else {
          int b = m >> 11, nn2 = m & 2047;
          int s = nn2 >> 4, rl = nn2 & 15;
          size_t base = ((size_t)((b * 128 + s) * 128 + rl)) * 768;
          out[base + n] = x[base + n] + v + bo[n];
        }
      }
    }
  }
}

// ---------------- MFMA flash attention (unchanged from round 2) ----------------
__global__ __launch_bounds__(256) void attn_kernel(
    const unsigned short* __restrict__ qw_g, const unsigned short* __restrict__ qr_g,
    const unsigned short* __restrict__ k_g, const unsigned short* __restrict__ vt_g,
    const unsigned short* __restrict__ rk_g, unsigned short* __restrict__ ao) {
  const int qt = blockIdx.x, hh = blockIdx.y, b = blockIdx.z;
  const int i0 = qt << 5;
  const int t = threadIdx.x;
  const int lane = t & 63, w = t >> 6;
  const int m16 = lane & 15, quad = lane >> 4;
  const int mi = w & 1, njb = w >> 1;
  const int sr = t >> 3, sg = t & 7;

  __shared__ __align__(16) short qw_s[32 * 64];
  __shared__ __align__(16) short qr_s[32 * 64];
  __shared__ __align__(16) short k_s[64 * 64];
  __shared__ __align__(16) short rk_s[96 * 64];
  __shared__ __align__(16) short vt_s[96 * 64];
  __shared__ __align__(16) short pb_s[32 * 64];
  __shared__ float p_s[32][68];
  __shared__ short t_s[32][104];
  __shared__ float alpha_s[32];
  __shared__ float linv_s[32];

  for (int u = t; u < 512; u += 256) {
    int tile = u >> 8, idx = u & 255, r = idx >> 3, ch = idx & 7;
    const unsigned short* src =
        (tile ? qr_g : qw_g) + (((size_t)(b * 2048 + i0 + r)) << 9) + (hh << 6) + (ch << 3);
    int4 vdat = *(const int4*)src;
    short* dst = (tile ? qr_s : qw_s) + r * 64 + (((ch ^ (r & 7))) << 3);
    *(int4*)dst = vdat;
  }

  float m_i = -1e30f, l_i = 0.f;
  f4 o0 = {0.f, 0.f, 0.f, 0.f}, o1 = o0, o2 = o0;
  const int arow = mi * 16 + m16;
  const int asw = arow & 7;
  const int crow = mi * 16 + quad * 4;
  const int brow0 = njb * 16 + m16;
  const int bsw = brow0 & 7;

  for (int j0 = 0; j0 < 2048; j0 += 64) {
    __syncthreads();
    for (int u = t; u < 512; u += 256) {
      int r = u >> 3, ch = u & 7;
      int4 vdat = *(const int4*)(k_g + (((size_t)(b * 2048 + j0 + r)) << 9) + (hh << 6) + (ch << 3));
      *(int4*)(k_s + r * 64 + ((ch ^ (r & 7)) << 3)) = vdat;
    }
    int rbase = 2047 + j0 - i0 - 31;
    for (int u = t; u < 760; u += 256) {
      int r = u >> 3, ch = u & 7;
      int4 vdat = *(const int4*)(rk_g + (((size_t)(rbase + r)) << 9) + (hh << 6) + (ch << 3));
      *(int4*)(rk_s + r * 64 + ((ch ^ (r & 7)) << 3)) = vdat;
    }
    for (int u = t; u < 768; u += 256) {
      int r = u >> 3, ch = u & 7;
      int4 vdat =
          *(const int4*)(vt_g + (((size_t)(b * 768 + hh * 96 + r)) << 11) + j0 + (ch << 3));
      *(int4*)(vt_s + r * 64 + ((ch ^ (r & 7)) << 3)) = vdat;
    }
    __syncthreads();

    f4 c0 = {0.f, 0.f, 0.f, 0.f}, c1 = c0;
    f4 r0 = c0, r1 = c0, r2 = c0;
#pragma unroll
    for (int kb = 0; kb < 2; ++kb) {
      int co = ((kb * 4 + quad) ^ asw) << 3;
      int cb = ((kb * 4 + quad) ^ bsw) << 3;
      s8v aq = *(const s8v*)(qw_s + arow * 64 + co);
      s8v ar = *(const s8v*)(qr_s + arow * 64 + co);
      s8v bk0 = *(const s8v*)(k_s + brow0 * 64 + cb);
      s8v bk1 = *(const s8v*)(k_s + (brow0 + 32) * 64 + cb);
      c0 = __builtin_amdgcn_mfma_f32_16x16x32_bf16(aq, bk0, c0, 0, 0, 0);
      c1 = __builtin_amdgcn_mfma_f32_16x16x32_bf16(aq, bk1, c1, 0, 0, 0);
      s8v br0 = *(const s8v*)(rk_s + brow0 * 64 + cb);
      s8v br1 = *(const s8v*)(rk_s + (brow0 + 32) * 64 + cb);
      s8v br2 = *(const s8v*)(rk_s + (brow0 + 64) * 64 + cb);
      r0 = __builtin_amdgcn_mfma_f32_16x16x32_bf16(ar, br0, r0, 0, 0, 0);
      r1 = __builtin_amdgcn_mfma_f32_16x16x32_bf16(ar, br1, r1, 0, 0, 0);
      r2 = __builtin_amdgcn_mfma_f32_16x16x32_bf16(ar, br2, r2, 0, 0, 0);
    }
#pragma unroll
    for (int rr = 0; rr < 4; ++rr) {
      p_s[crow + rr][njb * 16 + m16] = c0[rr];
      p_s[crow + rr][(njb + 2) * 16 + m16] = c1[rr];
      t_s[crow + rr][njb * 16 + m16] = (short)f2bf(r0[rr]);
      t_s[crow + rr][(njb + 2) * 16 + m16] = (short)f2bf(r1[rr]);
      t_s[crow + rr][(njb + 4) * 16 + m16] = (short)f2bf(r2[rr]);
    }
    __syncthreads();

    float sv[8];
    float mx = -1e30f;
#pragma unroll
    for (int j2 = 0; j2 < 8; ++j2) {
      int c = sg + (j2 << 3);
      float s = p_s[sr][c] + bf2f((unsigned short)t_s[sr][c - sr + 31]);
      sv[j2] = s;
      mx = fmaxf(mx, s);
    }
    mx = fmaxf(mx, __shfl_xor(mx, 1));
    mx = fmaxf(mx, __shfl_xor(mx, 2));
    mx = fmaxf(mx, __shfl_xor(mx, 4));
    float m_new = fmaxf(m_i, mx);
    float al = __expf(m_i - m_new);
    float sm = 0.f;
#pragma unroll
    for (int j2 = 0; j2 < 8; ++j2) {
      float p = __expf(sv[j2] - m_new);
      sm += p;
      pb_s[sr * 64 + ((j2 ^ (sr & 7)) << 3) + sg] = (short)f2bf(p);
    }
    sm += __shfl_xor(sm, 1);
    sm += __shfl_xor(sm, 2);
    sm += __shfl_xor(sm, 4);
    l_i = l_i * al + sm;
    m_i = m_new;
    if (sg == 0) alpha_s[sr] = al;
    __syncthreads();

#pragma unroll
    for (int rr = 0; rr < 4; ++rr) {
      float a = alpha_s[crow + rr];
      o0[rr] *= a; o1[rr] *= a; o2[rr] *= a;
    }
#pragma unroll
    for (int kb = 0; kb < 2; ++kb) {
      int co = ((kb * 4 + quad) ^ asw) << 3;
      int cb = ((kb * 4 + quad) ^ bsw) << 3;
      s8v ap = *(const s8v*)(pb_s + arow * 64 + co);
      s8v b0v = *(const s8v*)(vt_s + brow0 * 64 + cb);
      s8v b1v = *(const s8v*)(vt_s + (brow0 + 32) * 64 + cb);
      s8v b2v = *(const s8v*)(vt_s + (brow0 + 64) * 64 + cb);
      o0 = __builtin_amdgcn_mfma_f32_16x16x32_bf16(ap, b0v, o0, 0, 0, 0);
      o1 = __builtin_amdgcn_mfma_f32_16x16x32_bf16(ap, b1v, o1, 0, 0, 0);
      o2 = __builtin_amdgcn_mfma_f32_16x16x32_bf16(ap, b2v, o2, 0, 0, 0);
    }
  }

  if (sg == 0) linv_s[sr] = 1.f / l_i;
  __syncthreads();
#pragma unroll
  for (int rr = 0; rr < 4; ++rr) {
    int row = crow + rr;
    float inv = linv_s[row];
    size_t gbase = ((size_t)(b * 2048 + i0 + row)) * 768 + hh * 96;
    ao[gbase + njb * 16 + m16] = f2bf(o0[rr] * inv);
    ao[gbase + (njb + 2) * 16 + m16] = f2bf(o1[rr] * inv);
    ao[gbase + (njb + 4) * 16 + m16] = f2bf(o2[rr] * inv);
  }
}

// ---------------- launch ----------------
extern "C" void kernel_launch(void* const* d_in, const int* in_sizes, int n_in,
                              void* d_out, int out_size, void* d_ws, size_t ws_size,
                              hipStream_t stream) {
  (void)in_sizes; (void)n_in; (void)out_size; (void)ws_size;
  const float* x = (const float*)d_in[0];
  const float* ln_g = (const float*)d_in[1];
  const float* ln_b = (const float*)d_in[2];
  const float* Wq = (const float*)d_in[3];
  const float* Wk = (const float*)d_in[4];
  const float* Wv = (const float*)d_in[5];
  const float* Wr = (const float*)d_in[6];
  const float* rwb = (const float*)d_in[7];
  const float* rrb = (const float*)d_in[8];
  const float* Wo = (const float*)d_in[9];
  const float* bo = (const float*)d_in[10];
  const float* pe = (const float*)d_in[11];
  float* out = (float*)d_out;

  char* p = (char*)d_ws;
  unsigned short* hbf = (unsigned short*)p; p += (size_t)4096 * 768 * 2;
  unsigned short* qw = (unsigned short*)p;  p += (size_t)4096 * 512 * 2;
  unsigned short* qr = (unsigned short*)p;  p += (size_t)4096 * 512 * 2;
  unsigned short* kb = (unsigned short*)p;  p += (size_t)4096 * 512 * 2;
  unsigned short* vt = (unsigned short*)p;  p += (size_t)4096 * 768 * 2;
  unsigned short* rk = (unsigned short*)p;  p += (size_t)4095 * 512 * 2;
  unsigned short* ao = (unsigned short*)p;  p += (size_t)4096 * 768 * 2;
  unsigned short* Bt = (unsigned short*)p;  p += (size_t)1792 * 768 * 2;
  unsigned short* Bto = (unsigned short*)p;

  transp_cvt<<<dim3(12, 12, 4), dim3(256), 0, stream>>>(Wq, Wk, Wv, Wo, Bt, Bto);
  copy4<<<dim3(2048), dim3(256), 0, stream>>>((const float4*)x, (float4*)out, 6291456);
  ln_kernel<<<dim3(4096), dim3(256), 0, stream>>>(x, ln_g, ln_b, hbf);
  gemm_rel<<<dim3(8, 64), dim3(256), 0, stream>>>(pe, Wr, rk, 4095, 512, 96);
  gemm_mfma<0><<<dim3(14, 32), dim3(256), 0, stream>>>(hbf, Bt, qw, qr, kb, vt, rwb, rrb,
                                                       nullptr, nullptr, nullptr);
  attn_kernel<<<dim3(64, 8, 2), dim3(256), 0, stream>>>(qw, qr, kb, vt, rk, ao);
  gemm_mfma<1><<<dim3(6, 32), dim3(256), 0, stream>>>(ao, Bto, nullptr, nullptr, nullptr,
                                                      nullptr, nullptr, nullptr, x, bo, out);
}